// Round 4
// baseline (2670.202 us; speedup 1.0000x reference)
//
#include <hip/hip_runtime.h>
#include <hip/hip_bf16.h>

#define N_NODES   100000
#define N_EDGES   3200000
#define N_FEAT    500
#define HIDDEN    128
#define N_CLASSES 64
#define K_LAYERS  10
#define SL        (N_NODES * 8)   // floats per channel-slice (slice-major z layout)

typedef __attribute__((ext_vector_type(8))) short bf16x8;
typedef __attribute__((ext_vector_type(4))) float f32x4;

__device__ inline ushort f2bf_rn(float f) {
  unsigned u = __float_as_uint(f);
  unsigned r = (u + 0x7FFFu + ((u >> 16) & 1u)) >> 16;
  return (ushort)r;
}
__device__ inline float bf2f(ushort h) {
  return __uint_as_float(((unsigned)h) << 16);
}

// ---------------- degree histogram ----------------
__global__ void count_deg_k(const int* __restrict__ dst, int* __restrict__ cnt) {
  int e = blockIdx.x * blockDim.x + threadIdx.x;
  if (e < N_EDGES) atomicAdd(&cnt[dst[e]], 1);
}

__global__ void dinv_k(const int* __restrict__ cnt, float* __restrict__ dinv) {
  int i = blockIdx.x * blockDim.x + threadIdx.x;
  if (i < N_NODES) dinv[i] = rsqrtf((float)(cnt[i] + 1));  // +1 self-loop
}

// ---------------- exclusive scan (1 block, 1024 threads) ----------------
__global__ __launch_bounds__(1024) void scan_k(const int* __restrict__ cnt,
                                               int* __restrict__ offs) {
  __shared__ int sums[1024];
  const int CH = (N_NODES + 1023) / 1024;  // 98
  int t = threadIdx.x;
  int base = t * CH;
  int hi = min(base + CH, N_NODES);
  int s = 0;
  for (int i = base; i < hi; ++i) s += cnt[i];
  sums[t] = s;
  __syncthreads();
  for (int d = 1; d < 1024; d <<= 1) {
    int v = (t >= d) ? sums[t - d] : 0;
    __syncthreads();
    sums[t] += v;
    __syncthreads();
  }
  int run = sums[t] - s;  // exclusive prefix
  for (int i = base; i < hi; ++i) { offs[i] = run; run += cnt[i]; }
  if (t == 0) offs[N_NODES] = N_EDGES;
}

// ---------------- CSR fill (src + norm packed) ----------------
__global__ void fill_csr_k(const int* __restrict__ src, const int* __restrict__ dst,
                           const float* __restrict__ dinv, const int* __restrict__ offs,
                           int* __restrict__ cur, int2* __restrict__ csr) {
  int e = blockIdx.x * blockDim.x + threadIdx.x;
  if (e >= N_EDGES) return;
  int d = dst[e], s = src[e];
  int p = offs[d] + atomicAdd(&cur[d], 1);
  float w = dinv[s] * dinv[d];
  csr[p] = make_int2(s, __float_as_int(w));
}

// ---------------- W^T bf16 hi/lo prep: W[K][N] -> WT[N][KPAD] ----------------
__global__ void prep_wt_k(const float* __restrict__ W, ushort* __restrict__ hi,
                          ushort* __restrict__ lo, int K, int N, int KPAD) {
  int idx = blockIdx.x * 256 + threadIdx.x;
  if (idx >= N * KPAD) return;
  int n = idx / KPAD, k = idx - n * KPAD;
  float v = (k < K) ? W[(size_t)k * N + n] : 0.f;
  ushort h = f2bf_rn(v);
  ushort l = f2bf_rn(v - bf2f(h));
  hi[idx] = h;
  lo[idx] = l;
}

// ---------------- split-bf16 MFMA GEMM: C[M x BN] = A[M x KTOT] @ B + bias ----
// Block: 256 threads (4 waves as 2x2), tile 128 x BN, K-step 64.
// SLICE_OUT: write C in slice-major layout C[(col>>3)*SL + row*8 + (col&7)].
template<int BN, int KTOT, int KPAD, bool RELU, bool SLICE_OUT>
__global__ __launch_bounds__(256, 2) void mfma_gemm_k(
    const float* __restrict__ A, const ushort* __restrict__ BThi,
    const ushort* __restrict__ BTlo, const float* __restrict__ bias,
    float* __restrict__ C, int M) {
  constexpr int BK = 64;
  constexpr int NF = BN / 32;  // n-frags per wave
  __shared__ __align__(16) ushort sm[(2 * 128 + 2 * BN) * BK];
  ushort* Ahi = sm;
  ushort* Alo = sm + 128 * BK;
  ushort* Bhi = sm + 2 * 128 * BK;
  ushort* Blo = Bhi + BN * BK;

  int tid = threadIdx.x;
  int lane = tid & 63, wid = tid >> 6;
  int wm = wid >> 1, wn = wid & 1;
  int lrow = lane & 15, lg = lane >> 4;
  int row0 = blockIdx.x * 128;

  f32x4 acc[4][NF];
  #pragma unroll
  for (int m = 0; m < 4; ++m)
    #pragma unroll
    for (int n = 0; n < NF; ++n) acc[m][n] = (f32x4){0.f, 0.f, 0.f, 0.f};

  for (int kc = 0; kc < KPAD; kc += BK) {
    __syncthreads();
    // ---- stage A (fp32 -> bf16 hi/lo), 128 rows x 64 k ----
    #pragma unroll
    for (int i = 0; i < 8; ++i) {
      int c = tid + i * 256;               // 0..2047 (128 rows x 16 float4)
      int r = c >> 4, k4 = (c & 15) << 2;
      int gr = row0 + r, gk = kc + k4;
      float4 v = make_float4(0.f, 0.f, 0.f, 0.f);
      if (gr < M) {
        if (gk + 3 < KTOT) {
          v = *(const float4*)(A + (size_t)gr * KTOT + gk);
        } else {
          float* vp = &v.x;
          #pragma unroll
          for (int e = 0; e < 4; ++e)
            if (gk + e < KTOT) vp[e] = A[(size_t)gr * KTOT + gk + e];
        }
      }
      ushort h0 = f2bf_rn(v.x), h1 = f2bf_rn(v.y), h2 = f2bf_rn(v.z), h3 = f2bf_rn(v.w);
      ushort l0 = f2bf_rn(v.x - bf2f(h0)), l1 = f2bf_rn(v.y - bf2f(h1));
      ushort l2 = f2bf_rn(v.z - bf2f(h2)), l3 = f2bf_rn(v.w - bf2f(h3));
      int chunk = k4 >> 3, sub = k4 & 4;
      int ad = r * 64 + ((chunk << 3) ^ ((r & 7) << 3)) + sub;
      *(ushort4*)(Ahi + ad) = make_ushort4(h0, h1, h2, h3);
      *(ushort4*)(Alo + ad) = make_ushort4(l0, l1, l2, l3);
    }
    // ---- stage B (precomputed bf16 hi/lo, transposed), BN rows x 64 k ----
    #pragma unroll
    for (int i = 0; i < BN * 8 / 256; ++i) {
      int c = tid + i * 256;               // chunk id over BN*8
      int n = c >> 3, ch = c & 7;
      int gk = kc + ch * 8;
      int ad = n * 64 + ((ch << 3) ^ ((n & 7) << 3));
      *(uint4*)(Bhi + ad) = *(const uint4*)(BThi + (size_t)n * KPAD + gk);
      *(uint4*)(Blo + ad) = *(const uint4*)(BTlo + (size_t)n * KPAD + gk);
    }
    __syncthreads();
    // ---- MFMA: 2 k-subs of 32 ----
    #pragma unroll
    for (int ks = 0; ks < 2; ++ks) {
      bf16x8 ah[4], al[4], bh[NF], bl[NF];
      #pragma unroll
      for (int m = 0; m < 4; ++m) {
        int r = wm * 64 + m * 16 + lrow;
        int ad = r * 64 + (((ks * 4 + lg) << 3) ^ ((r & 7) << 3));
        ah[m] = *(const bf16x8*)(Ahi + ad);
        al[m] = *(const bf16x8*)(Alo + ad);
      }
      #pragma unroll
      for (int n = 0; n < NF; ++n) {
        int r = wn * (BN / 2) + n * 16 + lrow;
        int ad = r * 64 + (((ks * 4 + lg) << 3) ^ ((r & 7) << 3));
        bh[n] = *(const bf16x8*)(Bhi + ad);
        bl[n] = *(const bf16x8*)(Blo + ad);
      }
      #pragma unroll
      for (int m = 0; m < 4; ++m)
        #pragma unroll
        for (int n = 0; n < NF; ++n) {
          acc[m][n] = __builtin_amdgcn_mfma_f32_16x16x32_bf16(ah[m], bh[n], acc[m][n], 0, 0, 0);
          acc[m][n] = __builtin_amdgcn_mfma_f32_16x16x32_bf16(ah[m], bl[n], acc[m][n], 0, 0, 0);
          acc[m][n] = __builtin_amdgcn_mfma_f32_16x16x32_bf16(al[m], bh[n], acc[m][n], 0, 0, 0);
        }
    }
  }
  // ---- epilogue: C/D layout col=lane&15, row=(lane>>4)*4+reg (verified) ----
  #pragma unroll
  for (int m = 0; m < 4; ++m)
    #pragma unroll
    for (int n = 0; n < NF; ++n) {
      int gcol = wn * (BN / 2) + n * 16 + lrow;
      float bb = bias[gcol];
      #pragma unroll
      for (int r = 0; r < 4; ++r) {
        int grow = row0 + wm * 64 + m * 16 + lg * 4 + r;
        if (grow < M) {
          float v = acc[m][n][r] + bb;
          if (RELU) v = fmaxf(v, 0.f);
          if (SLICE_OUT)
            C[(size_t)(gcol >> 3) * SL + (size_t)grow * 8 + (gcol & 7)] = v;
          else
            C[(size_t)grow * BN + gcol] = v;
        }
      }
    }
}

// ---------------- propagation v3: channel-sliced, XCD-affine ----------------
// slice = blockIdx&7 (round-robin -> each XCD handles one 8-channel slice whose
// slice-major z region is 3.2MB and stays in that XCD's 4MB L2). Wave = one
// (node, slice): lane = (edge-subgroup 0..7) x (channel 0..7). csr entries
// broadcast via shfl; pad entries (s=0,w=0) hit a hot line, harmless.
__global__ __launch_bounds__(256) void prop_slice_k(const float* __restrict__ zin,
                                                    float* __restrict__ zout,
                                                    const float* __restrict__ h0sl,
                                                    const float* __restrict__ dinv,
                                                    const int* __restrict__ offs,
                                                    const int2* __restrict__ csr) {
  int lane = threadIdx.x & 63;
  int wid = threadIdx.x >> 6;
  int b = blockIdx.x;
  int slice = b & 7;
  int node = ((b >> 3) << 2) + wid;
  if (node >= N_NODES) return;
  int lc = lane & 7;   // channel within slice
  int ge = lane >> 3;  // edge subgroup 0..7
  const float* zsl = zin + (size_t)slice * SL;

  float acc = 0.f;
  int beg = offs[node], end = offs[node + 1];
  for (int e = beg; e < end; e += 64) {
    int2 v = (e + lane < end) ? csr[e + lane] : make_int2(0, 0);
    #pragma unroll
    for (int j = 0; j < 64; j += 8) {
      int s = __shfl(v.x, j + ge);
      float w = __int_as_float(__shfl(v.y, j + ge));
      acc += w * zsl[s * 8 + lc];
    }
  }
  // reduce the 8 edge-subgroup partials (lane bits 3,4,5)
  acc += __shfl_xor(acc, 8);
  acc += __shfl_xor(acc, 16);
  acc += __shfl_xor(acc, 32);
  if (ge == 0) {
    float di = dinv[node];
    size_t zi = (size_t)slice * SL + (size_t)node * 8 + lc;
    zout[zi] = 0.9f * (acc + di * di * zsl[node * 8 + lc]) + 0.1f * h0sl[zi];
  }
}

// ---------------- softmax over 64 classes (slice-major input) ----------------
__global__ __launch_bounds__(256) void softmax_k(const float* __restrict__ zsl,
                                                 float* __restrict__ out) {
  int lane = threadIdx.x & 63;
  int row = (blockIdx.x * 256 + threadIdx.x) >> 6;
  if (row >= N_NODES) return;
  float v = zsl[(size_t)(lane >> 3) * SL + (size_t)row * 8 + (lane & 7)];
  float m = v;
  #pragma unroll
  for (int o = 32; o > 0; o >>= 1) m = fmaxf(m, __shfl_xor(m, o));
  float ev = __expf(v - m);
  float s = ev;
  #pragma unroll
  for (int o = 32; o > 0; o >>= 1) s += __shfl_xor(s, o);
  out[(size_t)row * 64 + lane] = ev / s;
}

extern "C" void kernel_launch(void* const* d_in, const int* in_sizes, int n_in,
                              void* d_out, int out_size, void* d_ws, size_t ws_size,
                              hipStream_t stream) {
  const float* x  = (const float*)d_in[0];
  const int*   ei = (const int*)d_in[1];
  const float* W1 = (const float*)d_in[2];
  const float* b1 = (const float*)d_in[3];
  const float* W2 = (const float*)d_in[4];
  const float* b2 = (const float*)d_in[5];
  const int* src = ei;
  const int* dst = ei + N_EDGES;

  char* w = (char*)d_ws;
  // H (51.2MB) is dead after gemm2; zA/zB (slice-major, 25.6MB each) overlay it.
  float* H  = (float*)w;
  float* zA = H;
  float* zB = H + (size_t)N_NODES * 64;
  size_t off = (size_t)N_NODES * 128 * 4;                     // 51.2 MB
  int2*   csr   = (int2*)(w + off);   off += (size_t)N_EDGES * 8;  // 25.6 MB
  float*  dinv  = (float*)(w + off);  off += 512 * 1024;
  int*    cnt   = (int*)(w + off);    off += 512 * 1024;
  int*    offs  = (int*)(w + off);    off += 512 * 1024;
  int*    cur   = (int*)(w + off);    off += 512 * 1024;
  ushort* w1thi = (ushort*)(w + off); off += 128 * 512 * 2;
  ushort* w1tlo = (ushort*)(w + off); off += 128 * 512 * 2;
  ushort* w2thi = (ushort*)(w + off); off += 64 * 128 * 2;
  ushort* w2tlo = (ushort*)(w + off); off += 64 * 128 * 2;
  // h0 (slice-major) lives in d_out: dead once the last prop layer has read it,
  // then softmax overwrites d_out.
  float* h0sl = (float*)d_out;

  hipMemsetAsync(cnt, 0, N_NODES * 4, stream);
  hipMemsetAsync(cur, 0, N_NODES * 4, stream);

  count_deg_k<<<(N_EDGES + 255) / 256, 256, 0, stream>>>(dst, cnt);
  dinv_k<<<(N_NODES + 255) / 256, 256, 0, stream>>>(cnt, dinv);
  scan_k<<<1, 1024, 0, stream>>>(cnt, offs);
  fill_csr_k<<<(N_EDGES + 255) / 256, 256, 0, stream>>>(src, dst, dinv, offs, cur, csr);

  prep_wt_k<<<(128 * 512 + 255) / 256, 256, 0, stream>>>(W1, w1thi, w1tlo, 500, 128, 512);
  prep_wt_k<<<(64 * 128 + 255) / 256, 256, 0, stream>>>(W2, w2thi, w2tlo, 128, 64, 128);

  mfma_gemm_k<128, 500, 512, true, false><<<(N_NODES + 127) / 128, 256, 0, stream>>>(
      x, w1thi, w1tlo, b1, H, N_NODES);
  mfma_gemm_k<64, 128, 128, false, true><<<(N_NODES + 127) / 128, 256, 0, stream>>>(
      H, w2thi, w2tlo, b2, h0sl, N_NODES);

  const float* zi = h0sl;
  float* zo = zA;
  for (int it = 0; it < K_LAYERS; ++it) {
    prop_slice_k<<<(N_NODES / 4) * 8, 256, 0, stream>>>(zi, zo, h0sl, dinv, offs, csr);
    zi = zo;
    zo = (zo == zA) ? zB : zA;
  }
  softmax_k<<<(N_NODES * 64) / 256, 256, 0, stream>>>(zi, (float*)d_out);
}

// Round 6
// 1341.229 us; speedup vs baseline: 1.9909x; 1.9909x over previous
//
#include <hip/hip_runtime.h>
#include <hip/hip_bf16.h>
#include <hip/hip_fp16.h>

#define N_NODES   100000
#define N_EDGES   3200000
#define N_FEAT    500
#define HIDDEN    128
#define N_CLASSES 64
#define K_LAYERS  10

typedef __attribute__((ext_vector_type(8))) short bf16x8;
typedef __attribute__((ext_vector_type(4))) float f32x4;

__device__ inline ushort f2bf_rn(float f) {
  unsigned u = __float_as_uint(f);
  unsigned r = (u + 0x7FFFu + ((u >> 16) & 1u)) >> 16;
  return (ushort)r;
}
__device__ inline float bf2f(ushort h) {
  return __uint_as_float(((unsigned)h) << 16);
}
__device__ inline float2 h2f2(unsigned u) {
  __half2 h = *(__half2*)&u;
  return make_float2(__low2float(h), __high2float(h));
}
__device__ inline unsigned f2h2(float a, float b) {
  __half2 h = __floats2half2_rn(a, b);
  return *(unsigned*)&h;
}

// ---------------- degree histogram ----------------
__global__ void count_deg_k(const int* __restrict__ dst, int* __restrict__ cnt) {
  int e = blockIdx.x * blockDim.x + threadIdx.x;
  if (e < N_EDGES) atomicAdd(&cnt[dst[e]], 1);
}

__global__ void dinv_k(const int* __restrict__ cnt, float* __restrict__ dinv) {
  int i = blockIdx.x * blockDim.x + threadIdx.x;
  if (i < N_NODES) dinv[i] = rsqrtf((float)(cnt[i] + 1));  // +1 self-loop
}

// ---------------- exclusive scan (1 block, 1024 threads) ----------------
__global__ __launch_bounds__(1024) void scan_k(const int* __restrict__ cnt,
                                               int* __restrict__ offs) {
  __shared__ int sums[1024];
  const int CH = (N_NODES + 1023) / 1024;  // 98
  int t = threadIdx.x;
  int base = t * CH;
  int hi = min(base + CH, N_NODES);
  int s = 0;
  for (int i = base; i < hi; ++i) s += cnt[i];
  sums[t] = s;
  __syncthreads();
  for (int d = 1; d < 1024; d <<= 1) {
    int v = (t >= d) ? sums[t - d] : 0;
    __syncthreads();
    sums[t] += v;
    __syncthreads();
  }
  int run = sums[t] - s;  // exclusive prefix
  for (int i = base; i < hi; ++i) { offs[i] = run; run += cnt[i]; }
  if (t == 0) offs[N_NODES] = N_EDGES;
}

// ---------------- CSR fill (src index only; weights folded into y) ----------
__global__ void fill_csr_k(const int* __restrict__ src, const int* __restrict__ dst,
                           const int* __restrict__ offs, int* __restrict__ cur,
                           int* __restrict__ csr4) {
  int e = blockIdx.x * blockDim.x + threadIdx.x;
  if (e >= N_EDGES) return;
  int d = dst[e];
  int p = offs[d] + atomicAdd(&cur[d], 1);
  csr4[p] = src[e];
}

// ---------------- W^T bf16 hi/lo prep: W[K][N] -> WT[N][KPAD] ----------------
__global__ void prep_wt_k(const float* __restrict__ W, ushort* __restrict__ hi,
                          ushort* __restrict__ lo, int K, int N, int KPAD) {
  int idx = blockIdx.x * 256 + threadIdx.x;
  if (idx >= N * KPAD) return;
  int n = idx / KPAD, k = idx - n * KPAD;
  float v = (k < K) ? W[(size_t)k * N + n] : 0.f;
  ushort h = f2bf_rn(v);
  ushort l = f2bf_rn(v - bf2f(h));
  hi[idx] = h;
  lo[idx] = l;
}

// ---------------- split-bf16 MFMA GEMM: C[M x BN] = A[M x KTOT] @ B + bias ----
template<int BN, int KTOT, int KPAD, bool RELU>
__global__ __launch_bounds__(256, 2) void mfma_gemm_k(
    const float* __restrict__ A, const ushort* __restrict__ BThi,
    const ushort* __restrict__ BTlo, const float* __restrict__ bias,
    float* __restrict__ C, int M) {
  constexpr int BK = 64;
  constexpr int NF = BN / 32;  // n-frags per wave
  __shared__ __align__(16) ushort sm[(2 * 128 + 2 * BN) * BK];
  ushort* Ahi = sm;
  ushort* Alo = sm + 128 * BK;
  ushort* Bhi = sm + 2 * 128 * BK;
  ushort* Blo = Bhi + BN * BK;

  int tid = threadIdx.x;
  int lane = tid & 63, wid = tid >> 6;
  int wm = wid >> 1, wn = wid & 1;
  int lrow = lane & 15, lg = lane >> 4;
  int row0 = blockIdx.x * 128;

  f32x4 acc[4][NF];
  #pragma unroll
  for (int m = 0; m < 4; ++m)
    #pragma unroll
    for (int n = 0; n < NF; ++n) acc[m][n] = (f32x4){0.f, 0.f, 0.f, 0.f};

  for (int kc = 0; kc < KPAD; kc += BK) {
    __syncthreads();
    // ---- stage A (fp32 -> bf16 hi/lo), 128 rows x 64 k ----
    #pragma unroll
    for (int i = 0; i < 8; ++i) {
      int c = tid + i * 256;               // 0..2047 (128 rows x 16 float4)
      int r = c >> 4, k4 = (c & 15) << 2;
      int gr = row0 + r, gk = kc + k4;
      float4 v = make_float4(0.f, 0.f, 0.f, 0.f);
      if (gr < M) {
        if (gk + 3 < KTOT) {
          v = *(const float4*)(A + (size_t)gr * KTOT + gk);
        } else {
          float* vp = &v.x;
          #pragma unroll
          for (int e = 0; e < 4; ++e)
            if (gk + e < KTOT) vp[e] = A[(size_t)gr * KTOT + gk + e];
        }
      }
      ushort h0 = f2bf_rn(v.x), h1 = f2bf_rn(v.y), h2 = f2bf_rn(v.z), h3 = f2bf_rn(v.w);
      ushort l0 = f2bf_rn(v.x - bf2f(h0)), l1 = f2bf_rn(v.y - bf2f(h1));
      ushort l2 = f2bf_rn(v.z - bf2f(h2)), l3 = f2bf_rn(v.w - bf2f(h3));
      int chunk = k4 >> 3, sub = k4 & 4;
      int ad = r * 64 + ((chunk << 3) ^ ((r & 7) << 3)) + sub;
      *(ushort4*)(Ahi + ad) = make_ushort4(h0, h1, h2, h3);
      *(ushort4*)(Alo + ad) = make_ushort4(l0, l1, l2, l3);
    }
    // ---- stage B (precomputed bf16 hi/lo, transposed), BN rows x 64 k ----
    #pragma unroll
    for (int i = 0; i < BN * 8 / 256; ++i) {
      int c = tid + i * 256;               // chunk id over BN*8
      int n = c >> 3, ch = c & 7;
      int gk = kc + ch * 8;
      int ad = n * 64 + ((ch << 3) ^ ((n & 7) << 3));
      *(uint4*)(Bhi + ad) = *(const uint4*)(BThi + (size_t)n * KPAD + gk);
      *(uint4*)(Blo + ad) = *(const uint4*)(BTlo + (size_t)n * KPAD + gk);
    }
    __syncthreads();
    // ---- MFMA: 2 k-subs of 32 ----
    #pragma unroll
    for (int ks = 0; ks < 2; ++ks) {
      bf16x8 ah[4], al[4], bh[NF], bl[NF];
      #pragma unroll
      for (int m = 0; m < 4; ++m) {
        int r = wm * 64 + m * 16 + lrow;
        int ad = r * 64 + (((ks * 4 + lg) << 3) ^ ((r & 7) << 3));
        ah[m] = *(const bf16x8*)(Ahi + ad);
        al[m] = *(const bf16x8*)(Alo + ad);
      }
      #pragma unroll
      for (int n = 0; n < NF; ++n) {
        int r = wn * (BN / 2) + n * 16 + lrow;
        int ad = r * 64 + (((ks * 4 + lg) << 3) ^ ((r & 7) << 3));
        bh[n] = *(const bf16x8*)(Bhi + ad);
        bl[n] = *(const bf16x8*)(Blo + ad);
      }
      #pragma unroll
      for (int m = 0; m < 4; ++m)
        #pragma unroll
        for (int n = 0; n < NF; ++n) {
          acc[m][n] = __builtin_amdgcn_mfma_f32_16x16x32_bf16(ah[m], bh[n], acc[m][n], 0, 0, 0);
          acc[m][n] = __builtin_amdgcn_mfma_f32_16x16x32_bf16(ah[m], bl[n], acc[m][n], 0, 0, 0);
          acc[m][n] = __builtin_amdgcn_mfma_f32_16x16x32_bf16(al[m], bh[n], acc[m][n], 0, 0, 0);
        }
    }
  }
  // ---- epilogue: C/D layout col=lane&15, row=(lane>>4)*4+reg (verified) ----
  #pragma unroll
  for (int m = 0; m < 4; ++m)
    #pragma unroll
    for (int n = 0; n < NF; ++n) {
      int gcol = wn * (BN / 2) + n * 16 + lrow;
      float bb = bias[gcol];
      #pragma unroll
      for (int r = 0; r < 4; ++r) {
        int grow = row0 + wm * 64 + m * 16 + lg * 4 + r;
        if (grow < M) {
          float v = acc[m][n][r] + bb;
          if (RELU) v = fmaxf(v, 0.f);
          C[(size_t)grow * BN + gcol] = v;
        }
      }
    }
}

// ---------------- y0 = fp16(dinv * h0), row-major [N][64] ----------------
__global__ __launch_bounds__(256) void conv_y0_k(const float* __restrict__ h0,
                                                 const float* __restrict__ dinv,
                                                 uint2* __restrict__ y16) {
  int i = blockIdx.x * 256 + threadIdx.x;  // one float4 / uint2 per thread
  if (i >= N_NODES * 16) return;
  int node = i >> 4;
  float dv = dinv[node];
  float4 h4 = ((const float4*)h0)[i];
  y16[i] = make_uint2(f2h2(dv * h4.x, dv * h4.y), f2h2(dv * h4.z, dv * h4.w));
}

// ---------------- propagation: fp16 y-gather, weights folded ----------------
// y = dinv*z stored fp16 [N+1][64] (row 128B; row N_NODES is a zero pad row).
// Wave = one node: 16 lanes per edge-row (8B/lane), 4 edges per load group.
// agg_d = sum y[s]; z_new = 0.9*dinv_d*(agg + y_d) + 0.1*h0_d.
template<bool OUT32>
__global__ __launch_bounds__(256) void prop_k(const uint2* __restrict__ yin,
                                              void* __restrict__ out,
                                              const float* __restrict__ h0,
                                              const float* __restrict__ dinv,
                                              const int* __restrict__ offs,
                                              const int* __restrict__ csr4) {
  int lane = threadIdx.x & 63;
  int wid = threadIdx.x >> 6;
  int node = (blockIdx.x << 2) + wid;
  if (node >= N_NODES) return;
  int grp = lane >> 4;   // edge slot within group of 4
  int lc = lane & 15;    // uint2 slot within 64-ch row

  float4 acc = make_float4(0.f, 0.f, 0.f, 0.f);
  int beg = offs[node], end = offs[node + 1];
  for (int e = beg; e < end; e += 64) {
    int s = (e + lane < end) ? csr4[e + lane] : N_NODES;  // pad -> zero row
    int cnt = min(64, end - e);
    for (int j = 0; j < cnt; j += 16) {
      int s0 = __shfl(s, j + grp);
      int s1 = __shfl(s, j + 4 + grp);
      int s2 = __shfl(s, j + 8 + grp);
      int s3 = __shfl(s, j + 12 + grp);
      uint2 g0 = yin[(size_t)s0 * 16 + lc];
      uint2 g1 = yin[(size_t)s1 * 16 + lc];
      uint2 g2 = yin[(size_t)s2 * 16 + lc];
      uint2 g3 = yin[(size_t)s3 * 16 + lc];
      float2 a, b;
      a = h2f2(g0.x); b = h2f2(g0.y);
      acc.x += a.x; acc.y += a.y; acc.z += b.x; acc.w += b.y;
      a = h2f2(g1.x); b = h2f2(g1.y);
      acc.x += a.x; acc.y += a.y; acc.z += b.x; acc.w += b.y;
      a = h2f2(g2.x); b = h2f2(g2.y);
      acc.x += a.x; acc.y += a.y; acc.z += b.x; acc.w += b.y;
      a = h2f2(g3.x); b = h2f2(g3.y);
      acc.x += a.x; acc.y += a.y; acc.z += b.x; acc.w += b.y;
    }
  }
  // merge the 4 group-partials (lane bits 4,5)
  #pragma unroll
  for (int off = 16; off <= 32; off <<= 1) {
    acc.x += __shfl_xor(acc.x, off);
    acc.y += __shfl_xor(acc.y, off);
    acc.z += __shfl_xor(acc.z, off);
    acc.w += __shfl_xor(acc.w, off);
  }
  if (grp == 0) {
    // self term
    uint2 gs = yin[(size_t)node * 16 + lc];
    float2 a = h2f2(gs.x), b = h2f2(gs.y);
    acc.x += a.x; acc.y += a.y; acc.z += b.x; acc.w += b.y;
    float dv = dinv[node];
    float4 h4 = ((const float4*)h0)[(size_t)node * 16 + lc];
    float4 z;
    z.x = 0.9f * dv * acc.x + 0.1f * h4.x;
    z.y = 0.9f * dv * acc.y + 0.1f * h4.y;
    z.z = 0.9f * dv * acc.z + 0.1f * h4.z;
    z.w = 0.9f * dv * acc.w + 0.1f * h4.w;
    if (OUT32) {
      ((float4*)out)[(size_t)node * 16 + lc] = z;
    } else {
      ((uint2*)out)[(size_t)node * 16 + lc] =
          make_uint2(f2h2(dv * z.x, dv * z.y), f2h2(dv * z.z, dv * z.w));
    }
  }
}

// ---------------- softmax over 64 classes, one wave per row ----------------
__global__ __launch_bounds__(256) void softmax_k(const float* __restrict__ z,
                                                 float* __restrict__ out) {
  int lane = threadIdx.x & 63;
  int row = (blockIdx.x * 256 + threadIdx.x) >> 6;
  if (row >= N_NODES) return;
  float v = z[(size_t)row * 64 + lane];
  float m = v;
  #pragma unroll
  for (int o = 32; o > 0; o >>= 1) m = fmaxf(m, __shfl_xor(m, o));
  float ev = __expf(v - m);
  float s = ev;
  #pragma unroll
  for (int o = 32; o > 0; o >>= 1) s += __shfl_xor(s, o);
  out[(size_t)row * 64 + lane] = ev / s;
}

extern "C" void kernel_launch(void* const* d_in, const int* in_sizes, int n_in,
                              void* d_out, int out_size, void* d_ws, size_t ws_size,
                              hipStream_t stream) {
  const float* x  = (const float*)d_in[0];
  const int*   ei = (const int*)d_in[1];
  const float* W1 = (const float*)d_in[2];
  const float* b1 = (const float*)d_in[3];
  const float* W2 = (const float*)d_in[4];
  const float* b2 = (const float*)d_in[5];
  const int* src = ei;
  const int* dst = ei + N_EDGES;

  char* w = (char*)d_ws;
  // Layout (bytes):
  //   [0, 12.8M)        csr4 (src-only edge records)
  //   [12.8M, 64.0M)    H (gemm1 out / gemm2 in) -- dead after gemm2, overlaid:
  //        zA16 @12.8M (12.80M+pad), zB16 @25.7M (12.80M+pad), zF32 @38.6M (25.6M)
  //   [64.5M, ...)      dinv, cnt, offs, cur, weight-prep buffers
  int*    csr4 = (int*)w;
  float*  H    = (float*)(w + 12800000);
  uint2*  zA16 = (uint2*)(w + 12800000);
  uint2*  zB16 = (uint2*)(w + 25700000);
  float*  zF32 = (float*)(w + 38600000);
  float*  dinv = (float*)(w + 64500000);
  int*    cnt  = (int*)(w + 65000000);
  int*    offs = (int*)(w + 65500000);
  int*    cur  = (int*)(w + 66000000);
  ushort* w1thi = (ushort*)(w + 66500000);
  ushort* w1tlo = (ushort*)(w + 66700000);
  ushort* w2thi = (ushort*)(w + 66900000);
  ushort* w2tlo = (ushort*)(w + 67000000);
  float* h0 = (float*)d_out;  // fp32 [N][64]; dead once layer 9 reads it

  hipMemsetAsync(cnt, 0, N_NODES * 4, stream);
  hipMemsetAsync(cur, 0, N_NODES * 4, stream);

  count_deg_k<<<(N_EDGES + 255) / 256, 256, 0, stream>>>(dst, cnt);
  dinv_k<<<(N_NODES + 255) / 256, 256, 0, stream>>>(cnt, dinv);
  scan_k<<<1, 1024, 0, stream>>>(cnt, offs);
  fill_csr_k<<<(N_EDGES + 255) / 256, 256, 0, stream>>>(src, dst, offs, cur, csr4);

  prep_wt_k<<<(128 * 512 + 255) / 256, 256, 0, stream>>>(W1, w1thi, w1tlo, 500, 128, 512);
  prep_wt_k<<<(64 * 128 + 255) / 256, 256, 0, stream>>>(W2, w2thi, w2tlo, 128, 64, 128);

  mfma_gemm_k<128, 500, 512, true><<<(N_NODES + 127) / 128, 256, 0, stream>>>(
      x, w1thi, w1tlo, b1, H, N_NODES);
  mfma_gemm_k<64, 128, 128, false><<<(N_NODES + 127) / 128, 256, 0, stream>>>(
      H, w2thi, w2tlo, b2, h0, N_NODES);

  // Zero the pad rows (index N_NODES) of both fp16 y buffers. MUST happen
  // after the GEMMs: zA16/zB16 overlay H, and gemm1 would clobber the pads
  // (that was round 5's absmax=0.99 bug). prop_k never writes pad rows, so
  // they stay zero through all layers and graph replays.
  hipMemsetAsync((char*)zA16 + (size_t)N_NODES * 128, 0, 128, stream);
  hipMemsetAsync((char*)zB16 + (size_t)N_NODES * 128, 0, 128, stream);

  conv_y0_k<<<(N_NODES * 16 + 255) / 256, 256, 0, stream>>>(h0, dinv, zA16);

  const uint2* zi = zA16;
  uint2* zo = zB16;
  for (int it = 0; it < K_LAYERS - 1; ++it) {
    prop_k<false><<<(N_NODES + 3) / 4, 256, 0, stream>>>(zi, (void*)zo, h0, dinv, offs, csr4);
    zi = zo;
    zo = (zo == zA16) ? zB16 : zA16;
  }
  prop_k<true><<<(N_NODES + 3) / 4, 256, 0, stream>>>(zi, (void*)zF32, h0, dinv, offs, csr4);

  softmax_k<<<(N_NODES * 64) / 256, 256, 0, stream>>>(zF32, (float*)d_out);
}

// Round 7
// 1061.894 us; speedup vs baseline: 2.5146x; 1.2631x over previous
//
#include <hip/hip_runtime.h>
#include <hip/hip_bf16.h>
#include <hip/hip_fp16.h>

#define N_NODES   100000
#define N_EDGES   3200000
#define N_FEAT    500
#define HIDDEN    128
#define N_CLASSES 64
#define K_LAYERS  10
#define NBUCK     98          // ceil(N_NODES / 1024)

typedef __attribute__((ext_vector_type(8))) short bf16x8;
typedef __attribute__((ext_vector_type(4))) float f32x4;

__device__ inline ushort f2bf_rn(float f) {
  unsigned u = __float_as_uint(f);
  unsigned r = (u + 0x7FFFu + ((u >> 16) & 1u)) >> 16;
  return (ushort)r;
}
__device__ inline float bf2f(ushort h) {
  return __uint_as_float(((unsigned)h) << 16);
}
__device__ inline float2 h2f2(unsigned u) {
  __half2 h = *(__half2*)&u;
  return make_float2(__low2float(h), __high2float(h));
}
__device__ inline unsigned f2h2(float a, float b) {
  __half2 h = __floats2half2_rn(a, b);
  return *(unsigned*)&h;
}

// ============ CSR build via bucketed counting sort (no global scatter) ======
// Records packed as src | (dstLocal<<17); src < 2^17, dstLocal < 1024.

// (A) bucket histogram: LDS-aggregated, 98 global atomics per block
__global__ __launch_bounds__(256) void bucket_count_k(const int* __restrict__ dst,
                                                      int* __restrict__ bucket_cnt) {
  __shared__ int h[128];
  int t = threadIdx.x;
  if (t < 128) h[t] = 0;
  __syncthreads();
  for (int e = blockIdx.x * 256 + t; e < N_EDGES; e += gridDim.x * 256)
    atomicAdd(&h[dst[e] >> 10], 1);
  __syncthreads();
  if (t < 128 && h[t]) atomicAdd(&bucket_cnt[t], h[t]);
}

// (B) scan 128 bucket counts -> bases; init bcur; offs[N]=E
__global__ __launch_bounds__(128) void bucket_scan_k(const int* __restrict__ bucket_cnt,
                                                     int* __restrict__ bucket_base,
                                                     int* __restrict__ bcur,
                                                     int* __restrict__ offs) {
  __shared__ int sm[128];
  int t = threadIdx.x;
  int c = bucket_cnt[t];
  sm[t] = c;
  __syncthreads();
  for (int d = 1; d < 128; d <<= 1) {
    int v = (t >= d) ? sm[t - d] : 0;
    __syncthreads();
    sm[t] += v;
    __syncthreads();
  }
  int ex = sm[t] - c;  // exclusive prefix
  bucket_base[t] = ex;
  bcur[t] = ex;
  if (t == 127) bucket_base[128] = ex + c;  // == N_EDGES
  if (t == 0) offs[N_NODES] = N_EDGES;
}

// (C) bin edges into bucket-contiguous 'binned' (block-aggregated reservation)
#define BIN_CHUNK 12800   // 250 blocks * 12800 = 3.2M exactly
__global__ __launch_bounds__(256) void bin_scatter_k(const int* __restrict__ src,
                                                     const int* __restrict__ dst,
                                                     int* __restrict__ bcur,
                                                     int* __restrict__ binned) {
  __shared__ int h[128];
  __shared__ int hbase[128];
  int t = threadIdx.x;
  int e0 = blockIdx.x * BIN_CHUNK;
  int e1 = min(e0 + BIN_CHUNK, N_EDGES);
  if (t < 128) h[t] = 0;
  __syncthreads();
  for (int e = e0 + t; e < e1; e += 256) atomicAdd(&h[dst[e] >> 10], 1);
  __syncthreads();
  if (t < 128) {
    int c = h[t];
    hbase[t] = c ? atomicAdd(&bcur[t], c) : 0;
  }
  __syncthreads();
  if (t < 128) h[t] = 0;
  __syncthreads();
  for (int e = e0 + t; e < e1; e += 256) {
    int d = dst[e];
    int b = d >> 10;
    int pos = hbase[b] + atomicAdd(&h[b], 1);
    binned[pos] = (src[e] & 0x1FFFF) | ((d & 1023) << 17);
  }
}

// (D) per-bucket: LDS per-node histogram + scan -> offs, dinv, csr fill.
// All node-granular random accesses live in LDS; csr writes hit a 128KB window.
__global__ __launch_bounds__(256) void bucket_fill_k(const int* __restrict__ binned,
                                                     const int* __restrict__ bucket_base,
                                                     int* __restrict__ offs,
                                                     float* __restrict__ dinv,
                                                     int* __restrict__ csr4) {
  __shared__ int cnt[1024];
  __shared__ int tsum[256];
  int b = blockIdx.x;
  int base = bucket_base[b];
  int nE = bucket_base[b + 1] - base;
  int node0 = b << 10;
  int nN = min(1024, N_NODES - node0);
  int t = threadIdx.x;
  #pragma unroll
  for (int i = 0; i < 4; ++i) cnt[t + i * 256] = 0;
  __syncthreads();
  for (int i = t; i < nE; i += 256) atomicAdd(&cnt[binned[base + i] >> 17], 1);
  __syncthreads();
  int c0 = cnt[4 * t], c1 = cnt[4 * t + 1], c2 = cnt[4 * t + 2], c3 = cnt[4 * t + 3];
  int s = c0 + c1 + c2 + c3;
  tsum[t] = s;
  __syncthreads();
  for (int d = 1; d < 256; d <<= 1) {
    int v = (t >= d) ? tsum[t - d] : 0;
    __syncthreads();
    tsum[t] += v;
    __syncthreads();
  }
  int run = tsum[t] - s;  // exclusive
  int p0 = run, p1 = run + c0, p2 = p1 + c1, p3 = p2 + c2;
  if (4 * t + 0 < nN) { offs[node0 + 4 * t + 0] = base + p0; dinv[node0 + 4 * t + 0] = rsqrtf(c0 + 1.f); }
  if (4 * t + 1 < nN) { offs[node0 + 4 * t + 1] = base + p1; dinv[node0 + 4 * t + 1] = rsqrtf(c1 + 1.f); }
  if (4 * t + 2 < nN) { offs[node0 + 4 * t + 2] = base + p2; dinv[node0 + 4 * t + 2] = rsqrtf(c2 + 1.f); }
  if (4 * t + 3 < nN) { offs[node0 + 4 * t + 3] = base + p3; dinv[node0 + 4 * t + 3] = rsqrtf(c3 + 1.f); }
  __syncthreads();
  cnt[4 * t] = p0; cnt[4 * t + 1] = p1; cnt[4 * t + 2] = p2; cnt[4 * t + 3] = p3;
  __syncthreads();
  for (int i = t; i < nE; i += 256) {
    int rec = binned[base + i];
    int p = base + atomicAdd(&cnt[rec >> 17], 1);
    csr4[p] = rec & 0x1FFFF;
  }
}

// ---------------- W^T bf16 hi/lo prep: W[K][N] -> WT[N][KPAD] ----------------
__global__ void prep_wt_k(const float* __restrict__ W, ushort* __restrict__ hi,
                          ushort* __restrict__ lo, int K, int N, int KPAD) {
  int idx = blockIdx.x * 256 + threadIdx.x;
  if (idx >= N * KPAD) return;
  int n = idx / KPAD, k = idx - n * KPAD;
  float v = (k < K) ? W[(size_t)k * N + n] : 0.f;
  ushort h = f2bf_rn(v);
  ushort l = f2bf_rn(v - bf2f(h));
  hi[idx] = h;
  lo[idx] = l;
}

// ---------------- split-bf16 MFMA GEMM: C[M x BN] = A[M x KTOT] @ B + bias ----
template<int BN, int KTOT, int KPAD, bool RELU>
__global__ __launch_bounds__(256, 2) void mfma_gemm_k(
    const float* __restrict__ A, const ushort* __restrict__ BThi,
    const ushort* __restrict__ BTlo, const float* __restrict__ bias,
    float* __restrict__ C, int M) {
  constexpr int BK = 64;
  constexpr int NF = BN / 32;  // n-frags per wave
  __shared__ __align__(16) ushort sm[(2 * 128 + 2 * BN) * BK];
  ushort* Ahi = sm;
  ushort* Alo = sm + 128 * BK;
  ushort* Bhi = sm + 2 * 128 * BK;
  ushort* Blo = Bhi + BN * BK;

  int tid = threadIdx.x;
  int lane = tid & 63, wid = tid >> 6;
  int wm = wid >> 1, wn = wid & 1;
  int lrow = lane & 15, lg = lane >> 4;
  int row0 = blockIdx.x * 128;

  f32x4 acc[4][NF];
  #pragma unroll
  for (int m = 0; m < 4; ++m)
    #pragma unroll
    for (int n = 0; n < NF; ++n) acc[m][n] = (f32x4){0.f, 0.f, 0.f, 0.f};

  for (int kc = 0; kc < KPAD; kc += BK) {
    __syncthreads();
    // ---- stage A (fp32 -> bf16 hi/lo), 128 rows x 64 k ----
    #pragma unroll
    for (int i = 0; i < 8; ++i) {
      int c = tid + i * 256;               // 0..2047 (128 rows x 16 float4)
      int r = c >> 4, k4 = (c & 15) << 2;
      int gr = row0 + r, gk = kc + k4;
      float4 v = make_float4(0.f, 0.f, 0.f, 0.f);
      if (gr < M) {
        if (gk + 3 < KTOT) {
          v = *(const float4*)(A + (size_t)gr * KTOT + gk);
        } else {
          float* vp = &v.x;
          #pragma unroll
          for (int e = 0; e < 4; ++e)
            if (gk + e < KTOT) vp[e] = A[(size_t)gr * KTOT + gk + e];
        }
      }
      ushort h0 = f2bf_rn(v.x), h1 = f2bf_rn(v.y), h2 = f2bf_rn(v.z), h3 = f2bf_rn(v.w);
      ushort l0 = f2bf_rn(v.x - bf2f(h0)), l1 = f2bf_rn(v.y - bf2f(h1));
      ushort l2 = f2bf_rn(v.z - bf2f(h2)), l3 = f2bf_rn(v.w - bf2f(h3));
      int chunk = k4 >> 3, sub = k4 & 4;
      int ad = r * 64 + ((chunk << 3) ^ ((r & 7) << 3)) + sub;
      *(ushort4*)(Ahi + ad) = make_ushort4(h0, h1, h2, h3);
      *(ushort4*)(Alo + ad) = make_ushort4(l0, l1, l2, l3);
    }
    // ---- stage B (precomputed bf16 hi/lo, transposed), BN rows x 64 k ----
    #pragma unroll
    for (int i = 0; i < BN * 8 / 256; ++i) {
      int c = tid + i * 256;               // chunk id over BN*8
      int n = c >> 3, ch = c & 7;
      int gk = kc + ch * 8;
      int ad = n * 64 + ((ch << 3) ^ ((n & 7) << 3));
      *(uint4*)(Bhi + ad) = *(const uint4*)(BThi + (size_t)n * KPAD + gk);
      *(uint4*)(Blo + ad) = *(const uint4*)(BTlo + (size_t)n * KPAD + gk);
    }
    __syncthreads();
    // ---- MFMA: 2 k-subs of 32 ----
    #pragma unroll
    for (int ks = 0; ks < 2; ++ks) {
      bf16x8 ah[4], al[4], bh[NF], bl[NF];
      #pragma unroll
      for (int m = 0; m < 4; ++m) {
        int r = wm * 64 + m * 16 + lrow;
        int ad = r * 64 + (((ks * 4 + lg) << 3) ^ ((r & 7) << 3));
        ah[m] = *(const bf16x8*)(Ahi + ad);
        al[m] = *(const bf16x8*)(Alo + ad);
      }
      #pragma unroll
      for (int n = 0; n < NF; ++n) {
        int r = wn * (BN / 2) + n * 16 + lrow;
        int ad = r * 64 + (((ks * 4 + lg) << 3) ^ ((r & 7) << 3));
        bh[n] = *(const bf16x8*)(Bhi + ad);
        bl[n] = *(const bf16x8*)(Blo + ad);
      }
      #pragma unroll
      for (int m = 0; m < 4; ++m)
        #pragma unroll
        for (int n = 0; n < NF; ++n) {
          acc[m][n] = __builtin_amdgcn_mfma_f32_16x16x32_bf16(ah[m], bh[n], acc[m][n], 0, 0, 0);
          acc[m][n] = __builtin_amdgcn_mfma_f32_16x16x32_bf16(ah[m], bl[n], acc[m][n], 0, 0, 0);
          acc[m][n] = __builtin_amdgcn_mfma_f32_16x16x32_bf16(al[m], bh[n], acc[m][n], 0, 0, 0);
        }
    }
  }
  // ---- epilogue: C/D layout col=lane&15, row=(lane>>4)*4+reg (verified) ----
  #pragma unroll
  for (int m = 0; m < 4; ++m)
    #pragma unroll
    for (int n = 0; n < NF; ++n) {
      int gcol = wn * (BN / 2) + n * 16 + lrow;
      float bb = bias[gcol];
      #pragma unroll
      for (int r = 0; r < 4; ++r) {
        int grow = row0 + wm * 64 + m * 16 + lg * 4 + r;
        if (grow < M) {
          float v = acc[m][n][r] + bb;
          if (RELU) v = fmaxf(v, 0.f);
          C[(size_t)grow * BN + gcol] = v;
        }
      }
    }
}

// ---------------- y0 = fp16(dinv * h0), row-major [N][64] ----------------
__global__ __launch_bounds__(256) void conv_y0_k(const float* __restrict__ h0,
                                                 const float* __restrict__ dinv,
                                                 uint2* __restrict__ y16) {
  int i = blockIdx.x * 256 + threadIdx.x;  // one float4 / uint2 per thread
  if (i >= N_NODES * 16) return;
  int node = i >> 4;
  float dv = dinv[node];
  float4 h4 = ((const float4*)h0)[i];
  y16[i] = make_uint2(f2h2(dv * h4.x, dv * h4.y), f2h2(dv * h4.z, dv * h4.w));
}

// ---------------- propagation: fp16 y-gather, weights folded ----------------
// y = dinv*z stored fp16 [N+1][64] (row 128B; row N_NODES is a zero pad row).
// Wave = one node: 16 lanes per edge-row (8B/lane); 8 gathers in flight.
template<bool OUT32>
__global__ __launch_bounds__(256) void prop_k(const uint2* __restrict__ yin,
                                              void* __restrict__ out,
                                              const float* __restrict__ h0,
                                              const float* __restrict__ dinv,
                                              const int* __restrict__ offs,
                                              const int* __restrict__ csr4) {
  int lane = threadIdx.x & 63;
  int wid = threadIdx.x >> 6;
  int node = (blockIdx.x << 2) + wid;
  if (node >= N_NODES) return;
  int grp = lane >> 4;   // edge slot within group of 4
  int lc = lane & 15;    // uint2 slot within 64-ch row

  float4 acc = make_float4(0.f, 0.f, 0.f, 0.f);
  int beg = offs[node], end = offs[node + 1];
  for (int e = beg; e < end; e += 64) {
    int s = (e + lane < end) ? csr4[e + lane] : N_NODES;  // pad -> zero row
    int cnt = min(64, end - e);
    for (int j = 0; j < cnt; j += 32) {
      int sr[8];
      uint2 g[8];
      #pragma unroll
      for (int q = 0; q < 8; ++q) sr[q] = __shfl(s, j + 4 * q + grp);
      #pragma unroll
      for (int q = 0; q < 8; ++q) g[q] = yin[(size_t)sr[q] * 16 + lc];
      #pragma unroll
      for (int q = 0; q < 8; ++q) {
        float2 a = h2f2(g[q].x), b = h2f2(g[q].y);
        acc.x += a.x; acc.y += a.y; acc.z += b.x; acc.w += b.y;
      }
    }
  }
  // merge the 4 group-partials (lane bits 4,5)
  #pragma unroll
  for (int off = 16; off <= 32; off <<= 1) {
    acc.x += __shfl_xor(acc.x, off);
    acc.y += __shfl_xor(acc.y, off);
    acc.z += __shfl_xor(acc.z, off);
    acc.w += __shfl_xor(acc.w, off);
  }
  if (grp == 0) {
    // self term
    uint2 gs = yin[(size_t)node * 16 + lc];
    float2 a = h2f2(gs.x), b = h2f2(gs.y);
    acc.x += a.x; acc.y += a.y; acc.z += b.x; acc.w += b.y;
    float dv = dinv[node];
    float4 h4 = ((const float4*)h0)[(size_t)node * 16 + lc];
    float4 z;
    z.x = 0.9f * dv * acc.x + 0.1f * h4.x;
    z.y = 0.9f * dv * acc.y + 0.1f * h4.y;
    z.z = 0.9f * dv * acc.z + 0.1f * h4.z;
    z.w = 0.9f * dv * acc.w + 0.1f * h4.w;
    if (OUT32) {
      ((float4*)out)[(size_t)node * 16 + lc] = z;
    } else {
      ((uint2*)out)[(size_t)node * 16 + lc] =
          make_uint2(f2h2(dv * z.x, dv * z.y), f2h2(dv * z.z, dv * z.w));
    }
  }
}

// ---------------- softmax over 64 classes, one wave per row ----------------
__global__ __launch_bounds__(256) void softmax_k(const float* __restrict__ z,
                                                 float* __restrict__ out) {
  int lane = threadIdx.x & 63;
  int row = (blockIdx.x * 256 + threadIdx.x) >> 6;
  if (row >= N_NODES) return;
  float v = z[(size_t)row * 64 + lane];
  float m = v;
  #pragma unroll
  for (int o = 32; o > 0; o >>= 1) m = fmaxf(m, __shfl_xor(m, o));
  float ev = __expf(v - m);
  float s = ev;
  #pragma unroll
  for (int o = 32; o > 0; o >>= 1) s += __shfl_xor(s, o);
  out[(size_t)row * 64 + lane] = ev / s;
}

extern "C" void kernel_launch(void* const* d_in, const int* in_sizes, int n_in,
                              void* d_out, int out_size, void* d_ws, size_t ws_size,
                              hipStream_t stream) {
  const float* x  = (const float*)d_in[0];
  const int*   ei = (const int*)d_in[1];
  const float* W1 = (const float*)d_in[2];
  const float* b1 = (const float*)d_in[3];
  const float* W2 = (const float*)d_in[4];
  const float* b2 = (const float*)d_in[5];
  const int* src = ei;
  const int* dst = ei + N_EDGES;

  char* w = (char*)d_ws;
  // Layout (bytes):
  //   [0, 12.8M)        csr4
  //   [12.8M, 64.0M)    H (gemm1 out / gemm2 in) -- dead after gemm2, overlaid:
  //       zA16 @12.8M (+pad row @25.6M), zB16 @25.7M (+pad row @38.5M),
  //       zF32 @38.6M (25.6M) -- and 'binned' @38.6M (12.8M, setup-only, dead
  //       before gemm1 writes H)
  //   [64.5M, ...)      dinv, offs, bucket arrays, weight-prep buffers
  int*    csr4  = (int*)w;
  float*  H     = (float*)(w + 12800000);
  uint2*  zA16  = (uint2*)(w + 12800000);
  uint2*  zB16  = (uint2*)(w + 25700000);
  float*  zF32  = (float*)(w + 38600000);
  int*    binned = (int*)(w + 38600000);
  float*  dinv  = (float*)(w + 64500000);
  int*    offs  = (int*)(w + 65000000);
  int*    bucket_cnt  = (int*)(w + 66000000);   // 128 ints
  int*    bucket_base = (int*)(w + 66002048);   // 129 ints
  int*    bcur        = (int*)(w + 66004096);   // 128 ints
  ushort* w1thi = (ushort*)(w + 66500000);
  ushort* w1tlo = (ushort*)(w + 66700000);
  ushort* w2thi = (ushort*)(w + 66900000);
  ushort* w2tlo = (ushort*)(w + 67000000);
  float* h0 = (float*)d_out;  // fp32 [N][64]; dead once last layer reads it

  hipMemsetAsync(bucket_cnt, 0, 128 * 4, stream);

  // ---- CSR build (bucketed counting sort) ----
  bucket_count_k<<<512, 256, 0, stream>>>(dst, bucket_cnt);
  bucket_scan_k<<<1, 128, 0, stream>>>(bucket_cnt, bucket_base, bcur, offs);
  bin_scatter_k<<<N_EDGES / BIN_CHUNK, 256, 0, stream>>>(src, dst, bcur, binned);
  bucket_fill_k<<<NBUCK, 256, 0, stream>>>(binned, bucket_base, offs, dinv, csr4);

  // ---- MLP ----
  prep_wt_k<<<(128 * 512 + 255) / 256, 256, 0, stream>>>(W1, w1thi, w1tlo, 500, 128, 512);
  prep_wt_k<<<(64 * 128 + 255) / 256, 256, 0, stream>>>(W2, w2thi, w2tlo, 128, 64, 128);
  mfma_gemm_k<128, 500, 512, true><<<(N_NODES + 127) / 128, 256, 0, stream>>>(
      x, w1thi, w1tlo, b1, H, N_NODES);
  mfma_gemm_k<64, 128, 128, false><<<(N_NODES + 127) / 128, 256, 0, stream>>>(
      H, w2thi, w2tlo, b2, h0, N_NODES);

  // Zero the pad rows (index N_NODES) of both fp16 y buffers. MUST happen
  // after the GEMMs: zA16/zB16 overlay H and gemm1 would clobber the pads
  // (round 5's absmax=0.99 bug). prop_k never writes pad rows.
  hipMemsetAsync((char*)zA16 + (size_t)N_NODES * 128, 0, 128, stream);
  hipMemsetAsync((char*)zB16 + (size_t)N_NODES * 128, 0, 128, stream);

  conv_y0_k<<<(N_NODES * 16 + 255) / 256, 256, 0, stream>>>(h0, dinv, zA16);

  const uint2* zi = zA16;
  uint2* zo = zB16;
  for (int it = 0; it < K_LAYERS - 1; ++it) {
    prop_k<false><<<(N_NODES + 3) / 4, 256, 0, stream>>>(zi, (void*)zo, h0, dinv, offs, csr4);
    zi = zo;
    zo = (zo == zA16) ? zB16 : zA16;
  }
  prop_k<true><<<(N_NODES + 3) / 4, 256, 0, stream>>>(zi, (void*)zF32, h0, dinv, offs, csr4);

  softmax_k<<<(N_NODES * 64) / 256, 256, 0, stream>>>(zF32, (float*)d_out);
}